// Round 13
// baseline (118.771 us; speedup 1.0000x reference)
//
#include <hip/hip_runtime.h>

#define N_NODES 8192
#define D_IN 512
#define D_OUT 64
#define LRELU_ALPHA 0.2f

typedef __attribute__((ext_vector_type(8))) short bf16x8;
typedef __attribute__((ext_vector_type(4))) float f32x4;

__device__ __forceinline__ unsigned short f2bf(float x) {
    unsigned u = __float_as_uint(x);
    u += 0x7fffu + ((u >> 16) & 1u);   // round-to-nearest-even
    return (unsigned short)(u >> 16);
}

__device__ __forceinline__ float pgate(float mk, float w2v, float wh1v, float& lsum) {
    float e = wh1v + w2v;
    e = fmaxf(e, LRELU_ALPHA * e);   // LeakyReLU (monotone)
    float p = mk * __expf(e);        // mask is exactly 0.0/1.0; |e|<=~24 f32-safe
    lsum += p;
    return p;
}

// ---------------- Kernel 1: Wh = h @ W; epilogue writes WhTp(bf16, frag-order), Wh1, Wh2 ----------------
__global__ __launch_bounds__(256) void k_gemm_wh(const float* __restrict__ h,
                                                 const float* __restrict__ W,
                                                 const float* __restrict__ a,
                                                 unsigned short* __restrict__ WhTp,
                                                 float* __restrict__ Wh1,
                                                 float* __restrict__ Wh2) {
    __shared__ float hs[32][68];
    __shared__ float Ws[64][64];
    const int tid = threadIdx.x;
    const int r0 = blockIdx.x * 32;
    const int tf = tid & 15;
    const int tr = tid >> 4;
    float acc[2][4] = {{0.f,0.f,0.f,0.f},{0.f,0.f,0.f,0.f}};

    for (int kc = 0; kc < D_IN; kc += 64) {
        {
            int rr = tid >> 4;
            int cc = (tid & 15) * 4;
            float4 v0 = *(const float4*)&h[(size_t)(r0 + rr) * D_IN + kc + cc];
            float4 v1 = *(const float4*)&h[(size_t)(r0 + rr + 16) * D_IN + kc + cc];
            *(float4*)&hs[rr][cc] = v0;
            *(float4*)&hs[rr + 16][cc] = v1;
        }
        #pragma unroll
        for (int p = 0; p < 4; ++p) {
            int kk = (tid >> 4) + p * 16;
            int cc = (tid & 15) * 4;
            *(float4*)&Ws[kk][cc] = *(const float4*)&W[(size_t)(kc + kk) * D_OUT + cc];
        }
        __syncthreads();
        #pragma unroll
        for (int k = 0; k < 64; k += 4) {
            float4 a0 = *(const float4*)&hs[tr*2][k];
            float4 a1 = *(const float4*)&hs[tr*2+1][k];
            float av0[4] = {a0.x, a0.y, a0.z, a0.w};
            float av1[4] = {a1.x, a1.y, a1.z, a1.w};
            #pragma unroll
            for (int kk = 0; kk < 4; ++kk) {
                float4 b = *(const float4*)&Ws[k+kk][tf*4];
                acc[0][0] += av0[kk]*b.x; acc[0][1] += av0[kk]*b.y;
                acc[0][2] += av0[kk]*b.z; acc[0][3] += av0[kk]*b.w;
                acc[1][0] += av1[kk]*b.x; acc[1][1] += av1[kk]*b.y;
                acc[1][2] += av1[kk]*b.z; acc[1][3] += av1[kk]*b.w;
            }
        }
        __syncthreads();
    }
    const int orow = r0 + tr*2;   // even

    // permuted WhTp write: each MFMA B fragment is one contiguous 16B
    {
        const int blk = orow >> 6;
        const int cw  = orow & 63;
        const int d   = cw & 3;
        const int gg  = (cw >> 2) & 3;
        const int m   = cw >> 4;
        const int soff = blk * 64 + (m >> 1) * 32 + gg * 8 + (m & 1) * 4 + d;
        #pragma unroll
        for (int k = 0; k < 4; ++k) {
            unsigned v = (unsigned)f2bf(acc[0][k]) | ((unsigned)f2bf(acc[1][k]) << 16);
            *(unsigned*)&WhTp[(size_t)(tf*4 + k) * N_NODES + soff] = v;
        }
    }

    float a1v[4], a2v[4];
    #pragma unroll
    for (int k = 0; k < 4; ++k) { a1v[k] = a[tf*4 + k]; a2v[k] = a[64 + tf*4 + k]; }
    float s1 = 0.f, t1 = 0.f, s2 = 0.f, t2 = 0.f;
    #pragma unroll
    for (int k = 0; k < 4; ++k) {
        s1 += acc[0][k] * a1v[k];
        t1 += acc[1][k] * a1v[k];
        s2 += acc[0][k] * a2v[k];
        t2 += acc[1][k] * a2v[k];
    }
    #pragma unroll
    for (int d = 1; d < 16; d <<= 1) {
        s1 += __shfl_xor(s1, d);
        t1 += __shfl_xor(t1, d);
        s2 += __shfl_xor(s2, d);
        t2 += __shfl_xor(t2, d);
    }
    if (tf == 0) {
        Wh1[orow] = s1; Wh1[orow + 1] = t1;
        Wh2[orow] = s2; Wh2[orow + 1] = t2;
    }
}

// ---------------- Kernel 2: barriered dbuf DMA pipeline (m97 structure) + MFMA softmax/PV ----------------
// 512 blocks x 16-row strips, 32 chunks of 256 cols. Per chunk:
//   [ds_read M(par)] [B/W reg loads] [DMA chunk c+1 -> par^1] [pgate+MFMA] [__syncthreads]
// Ordering exploits in-order vmem retire: B/W are issued BEFORE the DMAs, so the
// compiler's wait at B/W first-use is vmcnt(4) (DMAs stay in flight); the only full
// drain is the compiler's own vmcnt(0) before s_barrier, issued AFTER compute has
// covered most of the DMA latency. Cross-block wave overlap (m114) absorbs the rest.
// No inline-asm waits anywhere -- the compiler keeps an exact, correct model.
__global__ __launch_bounds__(256, 3) void k_fused(const float* __restrict__ mask,
                                                  const unsigned short* __restrict__ WhTp,
                                                  const float* __restrict__ Wh1,
                                                  const float* __restrict__ Wh2,
                                                  float* __restrict__ out) {
    __shared__ float mbuf[2][4][16][64];   // 32 KB [par][wave][row][swizzled col]
    float (*accbuf)[16][68] = reinterpret_cast<float (*)[16][68]>(&mbuf[0][0][0][0]);
    float (*lsumbuf)[16]    = reinterpret_cast<float (*)[16]>((float*)mbuf + 4*16*68);

    const int tid  = threadIdx.x;
    const int wave = tid >> 6;
    const int lane = tid & 63;
    const int i16 = lane & 15;
    const int g   = lane >> 4;
    const int R   = blockIdx.x * 16;

    const float wh1v = Wh1[R + i16];
    const float* mstrip = mask + (size_t)R * N_NODES;

    f32x4 acc0 = {0.f,0.f,0.f,0.f}, acc1 = {0.f,0.f,0.f,0.f};
    f32x4 acc2 = {0.f,0.f,0.f,0.f}, acc3 = {0.f,0.f,0.f,0.f};
    float lsum = 0.f;

    // DMA for chunk c into parity p: 4 x 1KB, DMA j covers rows 4j..4j+3 of the wave's
    // 64-col window; per-lane source col pre-swizzled by row&7 (read applies same XOR).
#define DMA(c, p)                                                                      \
    {                                                                                  \
        const float* ms_ = mstrip + (size_t)(c) * 256 + wave * 64;                     \
        const float* s0_ = ms_ + (size_t)(0  + g) * N_NODES + ((i16 ^ ((0  + g) & 7)) << 2); \
        const float* s1_ = ms_ + (size_t)(4  + g) * N_NODES + ((i16 ^ ((4  + g) & 7)) << 2); \
        const float* s2_ = ms_ + (size_t)(8  + g) * N_NODES + ((i16 ^ ((8  + g) & 7)) << 2); \
        const float* s3_ = ms_ + (size_t)(12 + g) * N_NODES + ((i16 ^ ((12 + g) & 7)) << 2); \
        __builtin_amdgcn_global_load_lds(s0_, &mbuf[p][wave][ 0][0], 16, 0, 0);        \
        __builtin_amdgcn_global_load_lds(s1_, &mbuf[p][wave][ 4][0], 16, 0, 0);        \
        __builtin_amdgcn_global_load_lds(s2_, &mbuf[p][wave][ 8][0], 16, 0, 0);        \
        __builtin_amdgcn_global_load_lds(s3_, &mbuf[p][wave][12][0], 16, 0, 0);        \
    }

    // prologue: chunk 0 staged; barrier drains it (compiler vmcnt(0) before s_barrier)
    DMA(0, 0);
    __syncthreads();

    #pragma unroll 2
    for (int c = 0; c < 32; ++c) {
        const int par = c & 1;
        const int sw = i16 & 7;

        // M fragments for this lane's row (outstanding vmem == 0 here)
        const float4 M0 = *(const float4*)&mbuf[par][wave][i16][((0*4 + g) ^ sw) << 2];
        const float4 M1 = *(const float4*)&mbuf[par][wave][i16][((1*4 + g) ^ sw) << 2];
        const float4 M2 = *(const float4*)&mbuf[par][wave][i16][((2*4 + g) ^ sw) << 2];
        const float4 M3 = *(const float4*)&mbuf[par][wave][i16][((3*4 + g) ^ sw) << 2];

        // B fragments + Wh2 for chunk c (L2-hot), issued BEFORE the DMAs
        const unsigned short* bb = WhTp + (size_t)i16 * N_NODES
                                 + (size_t)(c * 4 + wave) * 64 + g * 8;
        const bf16x8 B0 = *(const bf16x8*)(bb);
        const bf16x8 B1 = *(const bf16x8*)(bb + 32);
        const bf16x8 B2 = *(const bf16x8*)(bb + 16 * N_NODES);
        const bf16x8 B3 = *(const bf16x8*)(bb + 16 * N_NODES + 32);
        const bf16x8 B4 = *(const bf16x8*)(bb + 32 * N_NODES);
        const bf16x8 B5 = *(const bf16x8*)(bb + 32 * N_NODES + 32);
        const bf16x8 B6 = *(const bf16x8*)(bb + 48 * N_NODES);
        const bf16x8 B7 = *(const bf16x8*)(bb + 48 * N_NODES + 32);
        const float* wp = Wh2 + c * 256 + wave * 64 + g * 4;
        const float4 W0 = *(const float4*)(wp);
        const float4 W1 = *(const float4*)(wp + 16);
        const float4 W2 = *(const float4*)(wp + 32);
        const float4 W3 = *(const float4*)(wp + 48);

        // prefetch next chunk (youngest vmem ops -> B/W waits leave these in flight)
        if (c + 1 < 32) DMA(c + 1, par ^ 1);
        __builtin_amdgcn_sched_barrier(0);

        bf16x8 af0, af1;
        af0[0] = (short)f2bf(pgate(M0.x, W0.x, wh1v, lsum));
        af0[1] = (short)f2bf(pgate(M0.y, W0.y, wh1v, lsum));
        af0[2] = (short)f2bf(pgate(M0.z, W0.z, wh1v, lsum));
        af0[3] = (short)f2bf(pgate(M0.w, W0.w, wh1v, lsum));
        af0[4] = (short)f2bf(pgate(M1.x, W1.x, wh1v, lsum));
        af0[5] = (short)f2bf(pgate(M1.y, W1.y, wh1v, lsum));
        af0[6] = (short)f2bf(pgate(M1.z, W1.z, wh1v, lsum));
        af0[7] = (short)f2bf(pgate(M1.w, W1.w, wh1v, lsum));
        af1[0] = (short)f2bf(pgate(M2.x, W2.x, wh1v, lsum));
        af1[1] = (short)f2bf(pgate(M2.y, W2.y, wh1v, lsum));
        af1[2] = (short)f2bf(pgate(M2.z, W2.z, wh1v, lsum));
        af1[3] = (short)f2bf(pgate(M2.w, W2.w, wh1v, lsum));
        af1[4] = (short)f2bf(pgate(M3.x, W3.x, wh1v, lsum));
        af1[5] = (short)f2bf(pgate(M3.y, W3.y, wh1v, lsum));
        af1[6] = (short)f2bf(pgate(M3.z, W3.z, wh1v, lsum));
        af1[7] = (short)f2bf(pgate(M3.w, W3.w, wh1v, lsum));

        acc0 = __builtin_amdgcn_mfma_f32_16x16x32_bf16(af0, B0, acc0, 0, 0, 0);
        acc1 = __builtin_amdgcn_mfma_f32_16x16x32_bf16(af0, B2, acc1, 0, 0, 0);
        acc2 = __builtin_amdgcn_mfma_f32_16x16x32_bf16(af0, B4, acc2, 0, 0, 0);
        acc3 = __builtin_amdgcn_mfma_f32_16x16x32_bf16(af0, B6, acc3, 0, 0, 0);
        acc0 = __builtin_amdgcn_mfma_f32_16x16x32_bf16(af1, B1, acc0, 0, 0, 0);
        acc1 = __builtin_amdgcn_mfma_f32_16x16x32_bf16(af1, B3, acc1, 0, 0, 0);
        acc2 = __builtin_amdgcn_mfma_f32_16x16x32_bf16(af1, B5, acc2, 0, 0, 0);
        acc3 = __builtin_amdgcn_mfma_f32_16x16x32_bf16(af1, B7, acc3, 0, 0, 0);

        __syncthreads();   // drains DMA(c+1); buf par free for c+2
    }
#undef DMA

    // lsum: sum the 4 g-subgroups holding the same row
    lsum += __shfl_xor(lsum, 16);
    lsum += __shfl_xor(lsum, 32);

    __syncthreads();   // mbuf dead; safe to alias as accbuf

    // D layout (m89): row = g*4 + r, col = i16
    #pragma unroll
    for (int r = 0; r < 4; ++r) {
        accbuf[wave][g*4 + r][ 0 + i16] = acc0[r];
        accbuf[wave][g*4 + r][16 + i16] = acc1[r];
        accbuf[wave][g*4 + r][32 + i16] = acc2[r];
        accbuf[wave][g*4 + r][48 + i16] = acc3[r];
    }
    if (lane < 16) lsumbuf[wave][lane] = lsum;
    __syncthreads();

    // merge 4 waves (disjoint col-windows), normalize, ELU, store
    const int tr  = tid >> 4;
    const int tf4 = (tid & 15) * 4;
    float4 s0 = *(const float4*)&accbuf[0][tr][tf4];
    float4 s1 = *(const float4*)&accbuf[1][tr][tf4];
    float4 s2 = *(const float4*)&accbuf[2][tr][tf4];
    float4 s3 = *(const float4*)&accbuf[3][tr][tf4];
    float L = lsumbuf[0][tr] + lsumbuf[1][tr] + lsumbuf[2][tr] + lsumbuf[3][tr];
    const float inv = (L > 0.f) ? 1.f / L : 0.f;
    float4 o;
    o.x = (s0.x + s1.x + s2.x + s3.x) * inv;
    o.y = (s0.y + s1.y + s2.y + s3.y) * inv;
    o.z = (s0.z + s1.z + s2.z + s3.z) * inv;
    o.w = (s0.w + s1.w + s2.w + s3.w) * inv;
    o.x = (o.x > 0.f) ? o.x : (__expf(o.x) - 1.f);
    o.y = (o.y > 0.f) ? o.y : (__expf(o.y) - 1.f);
    o.z = (o.z > 0.f) ? o.z : (__expf(o.z) - 1.f);
    o.w = (o.w > 0.f) ? o.w : (__expf(o.w) - 1.f);
    *(float4*)&out[(size_t)(R + tr) * D_OUT + tf4] = o;
}

extern "C" void kernel_launch(void* const* d_in, const int* in_sizes, int n_in,
                              void* d_out, int out_size, void* d_ws, size_t ws_size,
                              hipStream_t stream) {
    const float* h    = (const float*)d_in[0];
    const float* mask = (const float*)d_in[1];
    // d_in[2] = lamda: unused (dischange==0 makes the mask-update a no-op)
    const float* W    = (const float*)d_in[3];
    const float* a    = (const float*)d_in[4];
    float* out = (float*)d_out;

    // ws: WhTp bf16 [64][8192] (1MB) | Wh1 (32KB) | Wh2 (32KB)
    unsigned short* WhTp = (unsigned short*)d_ws;
    float* Wh1 = (float*)((char*)d_ws + (size_t)D_OUT * N_NODES * sizeof(unsigned short));
    float* Wh2 = Wh1 + N_NODES;

    k_gemm_wh<<<N_NODES / 32, 256, 0, stream>>>(h, W, a, WhTp, Wh1, Wh2);
    k_fused<<<N_NODES / 16, 256, 0, stream>>>(mask, WhTp, Wh1, Wh2, out);
}